// Round 2
// baseline (700.674 us; speedup 1.0000x reference)
//
#include <hip/hip_runtime.h>
#include <hip/hip_bf16.h>
#include <stdint.h>

#define DM 2048
#define SQ 2048
#define NB 2
#define NH 16
#define NKV 4
#define DK 128

typedef unsigned short u16;
typedef unsigned int u32;
typedef __attribute__((ext_vector_type(8))) __bf16 bf16x8;
typedef __attribute__((ext_vector_type(4))) float f32x4;
typedef __attribute__((ext_vector_type(8))) u16 u16x8;

__device__ __forceinline__ u16 f2bf(float f) {
  u32 x = __builtin_bit_cast(u32, f);
  x += 0x7fffu + ((x >> 16) & 1u);
  return (u16)(x >> 16);
}

__device__ __forceinline__ f32x4 mfma16(bf16x8 a, bf16x8 b, f32x4 c) {
  return __builtin_amdgcn_mfma_f32_16x16x32_bf16(a, b, c, 0, 0, 0);
}

#define GLDS16(g, l)                                                          \
  __builtin_amdgcn_global_load_lds(                                           \
      (const __attribute__((address_space(1))) void*)(g),                     \
      (__attribute__((address_space(3))) void*)(l), 16, 0, 0)

// ---------------- cast fp32 -> bf16 (8 elems/thread) ----------------
__global__ void cast_kernel(const float* __restrict__ src, u16* __restrict__ dst, int n8) {
  int i = blockIdx.x * blockDim.x + threadIdx.x;
  if (i >= n8) return;
  const float4* s4 = (const float4*)src;
  float4 a = s4[2 * i], b = s4[2 * i + 1];
  u16x8 v;
  v[0] = f2bf(a.x); v[1] = f2bf(a.y); v[2] = f2bf(a.z); v[3] = f2bf(a.w);
  v[4] = f2bf(b.x); v[5] = f2bf(b.y); v[6] = f2bf(b.z); v[7] = f2bf(b.w);
  *(u16x8*)(dst + 8 * (size_t)i) = v;
}

// ---------------- GEMM: C[M][N] = A[M][K](bf16) * W[N][K]^T(bf16) + bias ----------------
// 128x128 tile, BK=64, 4 waves each 64x64, global_load_lds w/ XOR swizzle.
__global__ __launch_bounds__(256) void gemm_bt(
    const u16* __restrict__ A, const u16* __restrict__ W,
    const float* __restrict__ bias, float* __restrict__ C,
    int M, int N, int K) {
  __shared__ u16 As[128 * 64];
  __shared__ u16 Bs[128 * 64];
  const int tid = threadIdx.x;
  const int w = tid >> 6, l = tid & 63;
  const int hi = l >> 4, lo = l & 15;
  const int MB = M >> 7;
  const int bm = blockIdx.x % MB, bn = blockIdx.x / MB;
  const int wr = w >> 1, wc = w & 1;
  const int lr8 = l >> 3, lc = l & 7;
  f32x4 acc[4][4] = {};
  for (int kt = 0; kt < K; kt += 64) {
#pragma unroll
    for (int i = 0; i < 4; ++i) {
      int row = w * 32 + i * 8 + lr8;
      int gc = lc ^ (row & 7);
      GLDS16(A + (size_t)(bm * 128 + row) * K + kt + gc * 8, &As[(w * 32 + i * 8) * 64]);
    }
#pragma unroll
    for (int i = 0; i < 4; ++i) {
      int row = w * 32 + i * 8 + lr8;
      int gc = lc ^ (row & 7);
      GLDS16(W + (size_t)(bn * 128 + row) * K + kt + gc * 8, &Bs[(w * 32 + i * 8) * 64]);
    }
    __syncthreads();
#pragma unroll
    for (int kk = 0; kk < 2; ++kk) {
      bf16x8 af[4], bf[4];
#pragma unroll
      for (int mi = 0; mi < 4; ++mi) {
        int row = wr * 64 + mi * 16 + lo;
        af[mi] = *(const bf16x8*)&As[row * 64 + (((kk * 4 + hi) ^ (row & 7)) * 8)];
      }
#pragma unroll
      for (int ni = 0; ni < 4; ++ni) {
        int row = wc * 64 + ni * 16 + lo;
        bf[ni] = *(const bf16x8*)&Bs[row * 64 + (((kk * 4 + hi) ^ (row & 7)) * 8)];
      }
#pragma unroll
      for (int mi = 0; mi < 4; ++mi)
#pragma unroll
        for (int ni = 0; ni < 4; ++ni)
          acc[mi][ni] = mfma16(af[mi], bf[ni], acc[mi][ni]);
    }
    __syncthreads();
  }
#pragma unroll
  for (int mi = 0; mi < 4; ++mi) {
#pragma unroll
    for (int ni = 0; ni < 4; ++ni) {
      int col = bn * 128 + wc * 64 + ni * 16 + lo;
      float bv = bias[col];
#pragma unroll
      for (int r = 0; r < 4; ++r) {
        int rowg = bm * 128 + wr * 64 + mi * 16 + hi * 4 + r;
        C[(size_t)rowg * N + col] = acc[mi][ni][r] + bv;
      }
    }
  }
}

// ---------------- RMSNorm + RoPE for q,k; one wave per head-vector ----------------
__global__ void normrope_qk(const float* __restrict__ qf, const float* __restrict__ kf,
                            const float* __restrict__ qw, const float* __restrict__ kw,
                            u16* __restrict__ qb, u16* __restrict__ kb) {
  int gw = (int)((blockIdx.x * (size_t)blockDim.x + threadIdx.x) >> 6);
  int lane = threadIdx.x & 63;
  int bs = gw / (NH + NKV), j = gw % (NH + NKV);
  int b = bs / SQ, s = bs % SQ;
  const float* src;
  const float* wgt;
  u16* dst;
  if (j < NH) {
    src = qf + (size_t)bs * DM + j * DK;
    wgt = qw;
    dst = qb + ((size_t)(b * NH + j) * SQ + s) * DK;
  } else {
    int kh = j - NH;
    src = kf + (size_t)bs * (NKV * DK) + kh * DK;
    wgt = kw;
    dst = kb + ((size_t)(b * NKV + kh) * SQ + s) * DK;
  }
  float2 xv = *(const float2*)(src + 2 * lane);
  float ss = xv.x * xv.x + xv.y * xv.y;
#pragma unroll
  for (int m = 1; m < 64; m <<= 1) ss += __shfl_xor(ss, m);
  float inv = rsqrtf(ss * (1.0f / DK) + 1e-8f);
  float x1 = xv.x * inv * wgt[2 * lane];
  float x2 = xv.y * inv * wgt[2 * lane + 1];
  // inv_freq = 10000^(-lane/64); theta = s * inv_freq
  float theta = (float)s * expf((float)lane * (-9.2103403720f / 64.0f));
  float sn, cs;
  sincosf(theta, &sn, &cs);
  float o1 = x1 * cs - x2 * sn;
  float o2 = x1 * sn + x2 * cs;
  u32 pack = (u32)f2bf(o1) | ((u32)f2bf(o2) << 16);
  *(u32*)(dst + 2 * lane) = pack;
}

// ---------------- V: cast + transpose to [B][NKV][DK][SQ] ----------------
__global__ __launch_bounds__(256) void vtrans(const float* __restrict__ vf, u16* __restrict__ vt) {
  __shared__ u16 T[128 * 72];
  int bid = blockIdx.x;
  int st = bid % (SQ / 64);
  int rem = bid / (SQ / 64);
  int vh = rem % NKV, b = rem / NKV;
  int s0 = st * 64;
  int t = threadIdx.x;
#pragma unroll
  for (int it = 0; it < 8; ++it) {
    int idx = it * 256 + t;  // 0..2047
    int sl = idx >> 5;       // 0..63
    int c4 = idx & 31;       // float4 within 128
    float4 v = *(const float4*)(vf + (size_t)(b * SQ + s0 + sl) * (NKV * DK) + vh * DK + c4 * 4);
    T[(c4 * 4 + 0) * 72 + sl] = f2bf(v.x);
    T[(c4 * 4 + 1) * 72 + sl] = f2bf(v.y);
    T[(c4 * 4 + 2) * 72 + sl] = f2bf(v.z);
    T[(c4 * 4 + 3) * 72 + sl] = f2bf(v.w);
  }
  __syncthreads();
#pragma unroll
  for (int it = 0; it < 4; ++it) {
    int idx = it * 256 + t;  // 0..1023
    int d = idx >> 3;        // 0..127
    int ch = idx & 7;        // 0..7
    u16x8 v = *(const u16x8*)&T[d * 72 + ch * 8];
    *(u16x8*)(vt + ((size_t)(b * NKV + vh) * DK + d) * SQ + s0 + ch * 8) = v;
  }
}

// ---------------- flash attention ----------------
// grid (SQ/64, NH, NB), 256 thr. wave w handles 16 Q rows. online softmax.
__global__ __launch_bounds__(256) void attn(const u16* __restrict__ qb, const u16* __restrict__ kb,
                                            const u16* __restrict__ vt, u16* __restrict__ out) {
  __shared__ u16 P[4][512];
  const int w = threadIdx.x >> 6, l = threadIdx.x & 63;
  const int hi = l >> 4, lo = l & 15;
  const int qt = blockIdx.x, h = blockIdx.y, b = blockIdx.z;
  const int kvh = h >> 2;
  const int q0 = qt * 64 + w * 16;
  const u16* Q = qb + (size_t)(b * NH + h) * SQ * DK;
  const u16* K = kb + (size_t)(b * NKV + kvh) * SQ * DK;
  const u16* V = vt + (size_t)(b * NKV + kvh) * DK * SQ;
  bf16x8 qf[4];
#pragma unroll
  for (int kk = 0; kk < 4; ++kk)
    qf[kk] = *(const bf16x8*)(Q + (size_t)(q0 + lo) * DK + kk * 32 + hi * 8);
  f32x4 oacc[8] = {};
  float mrun[4] = {-3e38f, -3e38f, -3e38f, -3e38f};
  float lrun[4] = {0.f, 0.f, 0.f, 0.f};
  const float scale = 0.08838834764831845f;  // 1/sqrt(128)
  const int nkv = q0 + 16;
  const int nt = (nkv + 31) >> 5;
  for (int ti = 0; ti < nt; ++ti) {
    const int kt = ti * 32;
    f32x4 sfr[2];
#pragma unroll
    for (int cb = 0; cb < 2; ++cb) {
      int kc0 = kt + cb * 16;
      f32x4 sf = {};
#pragma unroll
      for (int kk = 0; kk < 4; ++kk) {
        bf16x8 kfr = *(const bf16x8*)(K + (size_t)(kc0 + lo) * DK + kk * 32 + hi * 8);
        sf = mfma16(qf[kk], kfr, sf);
      }
#pragma unroll
      for (int r = 0; r < 4; ++r) {
        int row = q0 + hi * 4 + r;
        int col = kc0 + lo;
        sfr[cb][r] = (col > row) ? -1e30f : sf[r] * scale;
      }
    }
    float mnew[4], fsc[4];
#pragma unroll
    for (int r = 0; r < 4; ++r) {
      float t = fmaxf(sfr[0][r], sfr[1][r]);
      t = fmaxf(t, __shfl_xor(t, 1));
      t = fmaxf(t, __shfl_xor(t, 2));
      t = fmaxf(t, __shfl_xor(t, 4));
      t = fmaxf(t, __shfl_xor(t, 8));
      mnew[r] = fmaxf(mrun[r], t);
      fsc[r] = __expf(mrun[r] - mnew[r]);
      mrun[r] = mnew[r];
    }
#pragma unroll
    for (int r = 0; r < 4; ++r) {
      float p0 = __expf(sfr[0][r] - mnew[r]);
      float p1 = __expf(sfr[1][r] - mnew[r]);
      P[w][(hi * 4 + r) * 32 + lo] = f2bf(p0);
      P[w][(hi * 4 + r) * 32 + 16 + lo] = f2bf(p1);
      float rs = p0 + p1;
      rs += __shfl_xor(rs, 1);
      rs += __shfl_xor(rs, 2);
      rs += __shfl_xor(rs, 4);
      rs += __shfl_xor(rs, 8);
      lrun[r] = lrun[r] * fsc[r] + rs;
    }
#pragma unroll
    for (int fr = 0; fr < 8; ++fr)
#pragma unroll
      for (int r = 0; r < 4; ++r) oacc[fr][r] *= fsc[r];
    bf16x8 pa = *(const bf16x8*)&P[w][lo * 32 + hi * 8];
#pragma unroll
    for (int fr = 0; fr < 8; ++fr) {
      bf16x8 vfr = *(const bf16x8*)(V + (size_t)(fr * 16 + lo) * SQ + kt + hi * 8);
      oacc[fr] = mfma16(pa, vfr, oacc[fr]);
    }
  }
  float invl[4];
#pragma unroll
  for (int r = 0; r < 4; ++r) invl[r] = 1.0f / lrun[r];
#pragma unroll
  for (int fr = 0; fr < 8; ++fr) {
#pragma unroll
    for (int r = 0; r < 4; ++r) {
      int row = b * SQ + q0 + hi * 4 + r;
      int col = h * DK + fr * 16 + lo;
      out[(size_t)row * DM + col] = f2bf(oacc[fr][r] * invl[r]);
    }
  }
}

extern "C" void kernel_launch(void* const* d_in, const int* in_sizes, int n_in,
                              void* d_out, int out_size, void* d_ws, size_t ws_size,
                              hipStream_t stream) {
  const float* x = (const float*)d_in[0];
  const float* Wq = (const float*)d_in[1];
  const float* bq = (const float*)d_in[2];
  const float* Wk = (const float*)d_in[3];
  const float* bk = (const float*)d_in[4];
  const float* Wv = (const float*)d_in[5];
  const float* bv = (const float*)d_in[6];
  const float* Wo = (const float*)d_in[7];
  const float* bo = (const float*)d_in[8];
  const float* qw = (const float*)d_in[9];
  const float* kw = (const float*)d_in[10];
  float* outp = (float*)d_out;

  char* ws = (char*)d_ws;
  size_t off = 0;
  auto alloc = [&](size_t bytes) {
    char* p = ws + off;
    off += (bytes + 255) & ~(size_t)255;
    return p;
  };
  u16* xb = (u16*)alloc((size_t)NB * SQ * DM * 2);
  u16* Wqb = (u16*)alloc((size_t)DM * DM * 2);
  u16* Wkb = (u16*)alloc((size_t)NKV * DK * DM * 2);
  u16* Wvb = (u16*)alloc((size_t)NKV * DK * DM * 2);
  u16* Wob = (u16*)alloc((size_t)DM * DM * 2);
  float* qf32 = (float*)alloc((size_t)NB * SQ * DM * 4);
  float* kf32 = (float*)alloc((size_t)NB * SQ * NKV * DK * 4);
  float* vf32 = (float*)alloc((size_t)NB * SQ * NKV * DK * 4);
  u16* qbh = (u16*)alloc((size_t)NB * NH * SQ * DK * 2);
  u16* kbh = (u16*)alloc((size_t)NB * NKV * SQ * DK * 2);
  u16* vth = (u16*)alloc((size_t)NB * NKV * DK * SQ * 2);
  u16* aout = (u16*)alloc((size_t)NB * SQ * DM * 2);

  // casts
  {
    int n8 = NB * SQ * DM / 8;
    cast_kernel<<<(n8 + 255) / 256, 256, 0, stream>>>(x, xb, n8);
    n8 = DM * DM / 8;
    cast_kernel<<<(n8 + 255) / 256, 256, 0, stream>>>(Wq, Wqb, n8);
    cast_kernel<<<(n8 + 255) / 256, 256, 0, stream>>>(Wo, Wob, n8);
    n8 = NKV * DK * DM / 8;
    cast_kernel<<<(n8 + 255) / 256, 256, 0, stream>>>(Wk, Wkb, n8);
    cast_kernel<<<(n8 + 255) / 256, 256, 0, stream>>>(Wv, Wvb, n8);
  }
  // projections
  {
    int M = NB * SQ;
    gemm_bt<<<(M / 128) * (DM / 128), 256, 0, stream>>>(xb, Wqb, bq, qf32, M, DM, DM);
    gemm_bt<<<(M / 128) * ((NKV * DK) / 128), 256, 0, stream>>>(xb, Wkb, bk, kf32, M, NKV * DK, DM);
    gemm_bt<<<(M / 128) * ((NKV * DK) / 128), 256, 0, stream>>>(xb, Wvb, bv, vf32, M, NKV * DK, DM);
  }
  // norm + rope (q,k), transpose v
  {
    int waves = NB * SQ * (NH + NKV);
    normrope_qk<<<waves / 4, 256, 0, stream>>>(qf32, kf32, qw, kw, qbh, kbh);
    vtrans<<<NB * NKV * (SQ / 64), 256, 0, stream>>>(vf32, vth);
  }
  // attention
  {
    dim3 g(SQ / 64, NH, NB);
    attn<<<g, 256, 0, stream>>>(qbh, kbh, vth, aout);
  }
  // output projection
  {
    int M = NB * SQ;
    gemm_bt<<<(M / 128) * (DM / 128), 256, 0, stream>>>(aout, Wob, bo, outp, M, DM, DM);
  }
}

// Round 3
// 371.090 us; speedup vs baseline: 1.8882x; 1.8882x over previous
//
#include <hip/hip_runtime.h>
#include <hip/hip_bf16.h>
#include <stdint.h>

#define DM 2048
#define SQ 2048
#define NB 2
#define NH 16
#define NKV 4
#define DK 128

typedef unsigned short u16;
typedef unsigned int u32;
typedef __attribute__((ext_vector_type(8))) __bf16 bf16x8;
typedef __attribute__((ext_vector_type(4))) float f32x4;
typedef __attribute__((ext_vector_type(8))) u16 u16x8;

__device__ __forceinline__ u16 f2bf(float f) {
  u32 x = __builtin_bit_cast(u32, f);
  x += 0x7fffu + ((x >> 16) & 1u);
  return (u16)(x >> 16);
}

__device__ __forceinline__ f32x4 mfma16(bf16x8 a, bf16x8 b, f32x4 c) {
  return __builtin_amdgcn_mfma_f32_16x16x32_bf16(a, b, c, 0, 0, 0);
}

#define GLDS16(g, l)                                                          \
  __builtin_amdgcn_global_load_lds(                                           \
      (const __attribute__((address_space(1))) void*)(g),                     \
      (__attribute__((address_space(3))) void*)(l), 16, 0, 0)

// ---------------- cast fp32 -> bf16 (8 elems/thread) ----------------
__global__ void cast_kernel(const float* __restrict__ src, u16* __restrict__ dst, int n8) {
  int i = blockIdx.x * blockDim.x + threadIdx.x;
  if (i >= n8) return;
  const float4* s4 = (const float4*)src;
  float4 a = s4[2 * i], b = s4[2 * i + 1];
  u16x8 v;
  v[0] = f2bf(a.x); v[1] = f2bf(a.y); v[2] = f2bf(a.z); v[3] = f2bf(a.w);
  v[4] = f2bf(b.x); v[5] = f2bf(b.y); v[6] = f2bf(b.z); v[7] = f2bf(b.w);
  *(u16x8*)(dst + 8 * (size_t)i) = v;
}

// ---------------- GEMM: C[M][N] = A[M][K](bf16) * W[N][K]^T(bf16) + bias ----------------
__global__ __launch_bounds__(256) void gemm_bt(
    const u16* __restrict__ A, const u16* __restrict__ W,
    const float* __restrict__ bias, float* __restrict__ C,
    int M, int N, int K) {
  __shared__ u16 As[128 * 64];
  __shared__ u16 Bs[128 * 64];
  const int tid = threadIdx.x;
  const int w = tid >> 6, l = tid & 63;
  const int hi = l >> 4, lo = l & 15;
  const int MB = M >> 7;
  const int bm = blockIdx.x % MB, bn = blockIdx.x / MB;
  const int wr = w >> 1, wc = w & 1;
  const int lr8 = l >> 3, lc = l & 7;
  f32x4 acc[4][4] = {};
  for (int kt = 0; kt < K; kt += 64) {
#pragma unroll
    for (int i = 0; i < 4; ++i) {
      int row = w * 32 + i * 8 + lr8;
      int gc = lc ^ (row & 7);
      GLDS16(A + (size_t)(bm * 128 + row) * K + kt + gc * 8, &As[(w * 32 + i * 8) * 64]);
    }
#pragma unroll
    for (int i = 0; i < 4; ++i) {
      int row = w * 32 + i * 8 + lr8;
      int gc = lc ^ (row & 7);
      GLDS16(W + (size_t)(bn * 128 + row) * K + kt + gc * 8, &Bs[(w * 32 + i * 8) * 64]);
    }
    __syncthreads();
#pragma unroll
    for (int kk = 0; kk < 2; ++kk) {
      bf16x8 af[4], bf[4];
#pragma unroll
      for (int mi = 0; mi < 4; ++mi) {
        int row = wr * 64 + mi * 16 + lo;
        af[mi] = *(const bf16x8*)&As[row * 64 + (((kk * 4 + hi) ^ (row & 7)) * 8)];
      }
#pragma unroll
      for (int ni = 0; ni < 4; ++ni) {
        int row = wc * 64 + ni * 16 + lo;
        bf[ni] = *(const bf16x8*)&Bs[row * 64 + (((kk * 4 + hi) ^ (row & 7)) * 8)];
      }
#pragma unroll
      for (int mi = 0; mi < 4; ++mi)
#pragma unroll
        for (int ni = 0; ni < 4; ++ni)
          acc[mi][ni] = mfma16(af[mi], bf[ni], acc[mi][ni]);
    }
    __syncthreads();
  }
#pragma unroll
  for (int mi = 0; mi < 4; ++mi) {
#pragma unroll
    for (int ni = 0; ni < 4; ++ni) {
      int col = bn * 128 + wc * 64 + ni * 16 + lo;
      float bv = bias[col];
#pragma unroll
      for (int r = 0; r < 4; ++r) {
        int rowg = bm * 128 + wr * 64 + mi * 16 + hi * 4 + r;
        C[(size_t)rowg * N + col] = acc[mi][ni][r] + bv;
      }
    }
  }
}

// ---------------- RMSNorm + RoPE for q,k; one wave per head-vector ----------------
__global__ void normrope_qk(const float* __restrict__ qf, const float* __restrict__ kf,
                            const float* __restrict__ qw, const float* __restrict__ kw,
                            u16* __restrict__ qb, u16* __restrict__ kb) {
  int gw = (int)((blockIdx.x * (size_t)blockDim.x + threadIdx.x) >> 6);
  int lane = threadIdx.x & 63;
  int bs = gw / (NH + NKV), j = gw % (NH + NKV);
  int b = bs / SQ, s = bs % SQ;
  const float* src;
  const float* wgt;
  u16* dst;
  if (j < NH) {
    src = qf + (size_t)bs * DM + j * DK;
    wgt = qw;
    dst = qb + ((size_t)(b * NH + j) * SQ + s) * DK;
  } else {
    int kh = j - NH;
    src = kf + (size_t)bs * (NKV * DK) + kh * DK;
    wgt = kw;
    dst = kb + ((size_t)(b * NKV + kh) * SQ + s) * DK;
  }
  float2 xv = *(const float2*)(src + 2 * lane);
  float ss = xv.x * xv.x + xv.y * xv.y;
#pragma unroll
  for (int m = 1; m < 64; m <<= 1) ss += __shfl_xor(ss, m);
  float inv = rsqrtf(ss * (1.0f / DK) + 1e-8f);
  float x1 = xv.x * inv * wgt[2 * lane];
  float x2 = xv.y * inv * wgt[2 * lane + 1];
  float theta = (float)s * expf((float)lane * (-9.2103403720f / 64.0f));
  float sn, cs;
  sincosf(theta, &sn, &cs);
  float o1 = x1 * cs - x2 * sn;
  float o2 = x1 * sn + x2 * cs;
  u32 pack = (u32)f2bf(o1) | ((u32)f2bf(o2) << 16);
  *(u32*)(dst + 2 * lane) = pack;
}

// ---------------- V: cast + transpose to [B][NKV][DK][SQ] ----------------
__global__ __launch_bounds__(256) void vtrans(const float* __restrict__ vf, u16* __restrict__ vt) {
  __shared__ u16 T[128 * 72];
  int bid = blockIdx.x;
  int st = bid % (SQ / 64);
  int rem = bid / (SQ / 64);
  int vh = rem % NKV, b = rem / NKV;
  int s0 = st * 64;
  int t = threadIdx.x;
#pragma unroll
  for (int it = 0; it < 8; ++it) {
    int idx = it * 256 + t;  // 0..2047
    int sl = idx >> 5;       // 0..63
    int c4 = idx & 31;       // float4 within 128
    float4 v = *(const float4*)(vf + (size_t)(b * SQ + s0 + sl) * (NKV * DK) + vh * DK + c4 * 4);
    T[(c4 * 4 + 0) * 72 + sl] = f2bf(v.x);
    T[(c4 * 4 + 1) * 72 + sl] = f2bf(v.y);
    T[(c4 * 4 + 2) * 72 + sl] = f2bf(v.z);
    T[(c4 * 4 + 3) * 72 + sl] = f2bf(v.w);
  }
  __syncthreads();
#pragma unroll
  for (int it = 0; it < 4; ++it) {
    int idx = it * 256 + t;  // 0..1023
    int d = idx >> 3;        // 0..127
    int ch = idx & 7;        // 0..7
    u16x8 v = *(const u16x8*)&T[d * 72 + ch * 8];
    *(u16x8*)(vt + ((size_t)(b * NKV + vh) * DK + d) * SQ + s0 + ch * 8) = v;
  }
}

// ---------------- flash attention (LDS-staged, KVBLK=64) ----------------
// grid (SQ/64, NH, NB), 256 thr = 4 waves; wave w owns Q rows q0b+w*16..+15.
// K tile [64][128] and V^T tile [128][64] staged via global_load_lds with
// both-sides XOR chunk swizzle; P transposed through swizzled LDS.
__global__ __launch_bounds__(256) void attn(const u16* __restrict__ qb, const u16* __restrict__ kb,
                                            const u16* __restrict__ vt, u16* __restrict__ out) {
  __shared__ u16 Ks[64 * 128];   // [s][d], 16 chunks/row
  __shared__ u16 Vs[128 * 64];   // [d][s], 8 chunks/row
  __shared__ u16 P[4][16 * 64];  // per-wave [m][kv], 8 chunks/row
  const int w = threadIdx.x >> 6, l = threadIdx.x & 63;
  const int hi = l >> 4, lo = l & 15;
  const int qt = blockIdx.x, h = blockIdx.y, b = blockIdx.z;
  const int kvh = h >> 2;
  const int q0 = qt * 64 + w * 16;
  const u16* Q = qb + (size_t)(b * NH + h) * SQ * DK;
  const u16* K = kb + (size_t)(b * NKV + kvh) * SQ * DK;
  const u16* V = vt + (size_t)(b * NKV + kvh) * DK * SQ;
  bf16x8 qf[4];
#pragma unroll
  for (int kk = 0; kk < 4; ++kk)
    qf[kk] = *(const bf16x8*)(Q + (size_t)(q0 + lo) * DK + kk * 32 + hi * 8);
  f32x4 oacc[8] = {};
  float mrun[4] = {-3e38f, -3e38f, -3e38f, -3e38f};
  float lrun[4] = {0.f, 0.f, 0.f, 0.f};
  const float scale = 0.08838834764831845f;  // 1/sqrt(128)
  const int nt = qt + 1;
  for (int ti = 0; ti < nt; ++ti) {
    const int kt = ti * 64;
    // ---- stage K tile: 4 rows per GLDS (16 chunks/row), wave w -> rows w*16+i*4..
#pragma unroll
    for (int i = 0; i < 4; ++i) {
      int rb = w * 16 + i * 4;
      int row = rb + (l >> 4);
      int gc = (l & 15) ^ (row & 7);
      GLDS16(K + (size_t)(kt + row) * DK + gc * 8, &Ks[rb * 128]);
    }
    // ---- stage V^T tile: 8 rows per GLDS (8 chunks/row), wave w -> rows w*32+i*8..
#pragma unroll
    for (int i = 0; i < 4; ++i) {
      int rb = w * 32 + i * 8;
      int row = rb + (l >> 3);
      int gc = (l & 7) ^ (row & 7);
      GLDS16(V + (size_t)row * SQ + kt + gc * 8, &Vs[rb * 64]);
    }
    __syncthreads();
    // ---- QK^T: 4 col-blocks of 16
    f32x4 sfr[4];
    __builtin_amdgcn_s_setprio(1);
#pragma unroll
    for (int cb = 0; cb < 4; ++cb) {
      f32x4 sf = {};
#pragma unroll
      for (int kk = 0; kk < 4; ++kk) {
        int row = cb * 16 + lo;
        bf16x8 kfr = *(const bf16x8*)&Ks[row * 128 + (((kk * 4 + hi) ^ (row & 7)) * 8)];
        sf = mfma16(qf[kk], kfr, sf);
      }
      sfr[cb] = sf;
    }
    __builtin_amdgcn_s_setprio(0);
    // ---- mask + scale
#pragma unroll
    for (int cb = 0; cb < 4; ++cb) {
#pragma unroll
      for (int r = 0; r < 4; ++r) {
        int rowq = q0 + hi * 4 + r;
        int col = kt + cb * 16 + lo;
        sfr[cb][r] = (col > rowq) ? -1e30f : sfr[cb][r] * scale;
      }
    }
    // ---- online softmax over 64 cols
    float fsc[4];
#pragma unroll
    for (int r = 0; r < 4; ++r) {
      float t = fmaxf(fmaxf(sfr[0][r], sfr[1][r]), fmaxf(sfr[2][r], sfr[3][r]));
      t = fmaxf(t, __shfl_xor(t, 1));
      t = fmaxf(t, __shfl_xor(t, 2));
      t = fmaxf(t, __shfl_xor(t, 4));
      t = fmaxf(t, __shfl_xor(t, 8));
      float mnew = fmaxf(mrun[r], t);
      fsc[r] = __expf(mrun[r] - mnew);
      mrun[r] = mnew;
      int prow = hi * 4 + r;
      float rs = 0.f;
#pragma unroll
      for (int cb = 0; cb < 4; ++cb) {
        float p = __expf(sfr[cb][r] - mnew);
        rs += p;
        int chunk = cb * 2 + (lo >> 3);
        P[w][prow * 64 + ((chunk ^ (prow & 7)) * 8) + (lo & 7)] = f2bf(p);
      }
      rs += __shfl_xor(rs, 1);
      rs += __shfl_xor(rs, 2);
      rs += __shfl_xor(rs, 4);
      rs += __shfl_xor(rs, 8);
      lrun[r] = lrun[r] * fsc[r] + rs;
    }
    // ---- rescale O
#pragma unroll
    for (int fr = 0; fr < 8; ++fr)
#pragma unroll
      for (int r = 0; r < 4; ++r) oacc[fr][r] *= fsc[r];
    // ---- PV: 2 k-halves of 32
    __builtin_amdgcn_s_setprio(1);
#pragma unroll
    for (int half = 0; half < 2; ++half) {
      bf16x8 pa = *(const bf16x8*)&P[w][lo * 64 + (((half * 4 + hi) ^ (lo & 7)) * 8)];
#pragma unroll
      for (int fr = 0; fr < 8; ++fr) {
        int row = fr * 16 + lo;
        bf16x8 vfr = *(const bf16x8*)&Vs[row * 64 + (((half * 4 + hi) ^ (row & 7)) * 8)];
        oacc[fr] = mfma16(pa, vfr, oacc[fr]);
      }
    }
    __builtin_amdgcn_s_setprio(0);
    __syncthreads();
  }
  float invl[4];
#pragma unroll
  for (int r = 0; r < 4; ++r) invl[r] = 1.0f / lrun[r];
#pragma unroll
  for (int fr = 0; fr < 8; ++fr) {
#pragma unroll
    for (int r = 0; r < 4; ++r) {
      int row = b * SQ + q0 + hi * 4 + r;
      int col = h * DK + fr * 16 + lo;
      out[(size_t)row * DM + col] = f2bf(oacc[fr][r] * invl[r]);
    }
  }
}

extern "C" void kernel_launch(void* const* d_in, const int* in_sizes, int n_in,
                              void* d_out, int out_size, void* d_ws, size_t ws_size,
                              hipStream_t stream) {
  const float* x = (const float*)d_in[0];
  const float* Wq = (const float*)d_in[1];
  const float* bq = (const float*)d_in[2];
  const float* Wk = (const float*)d_in[3];
  const float* bk = (const float*)d_in[4];
  const float* Wv = (const float*)d_in[5];
  const float* bv = (const float*)d_in[6];
  const float* Wo = (const float*)d_in[7];
  const float* bo = (const float*)d_in[8];
  const float* qw = (const float*)d_in[9];
  const float* kw = (const float*)d_in[10];
  float* outp = (float*)d_out;

  char* ws = (char*)d_ws;
  size_t off = 0;
  auto alloc = [&](size_t bytes) {
    char* p = ws + off;
    off += (bytes + 255) & ~(size_t)255;
    return p;
  };
  u16* xb = (u16*)alloc((size_t)NB * SQ * DM * 2);
  u16* Wqb = (u16*)alloc((size_t)DM * DM * 2);
  u16* Wkb = (u16*)alloc((size_t)NKV * DK * DM * 2);
  u16* Wvb = (u16*)alloc((size_t)NKV * DK * DM * 2);
  u16* Wob = (u16*)alloc((size_t)DM * DM * 2);
  float* qf32 = (float*)alloc((size_t)NB * SQ * DM * 4);
  float* kf32 = (float*)alloc((size_t)NB * SQ * NKV * DK * 4);
  float* vf32 = (float*)alloc((size_t)NB * SQ * NKV * DK * 4);
  u16* qbh = (u16*)alloc((size_t)NB * NH * SQ * DK * 2);
  u16* kbh = (u16*)alloc((size_t)NB * NKV * SQ * DK * 2);
  u16* vth = (u16*)alloc((size_t)NB * NKV * DK * SQ * 2);
  u16* aout = (u16*)alloc((size_t)NB * SQ * DM * 2);

  // casts
  {
    int n8 = NB * SQ * DM / 8;
    cast_kernel<<<(n8 + 255) / 256, 256, 0, stream>>>(x, xb, n8);
    n8 = DM * DM / 8;
    cast_kernel<<<(n8 + 255) / 256, 256, 0, stream>>>(Wq, Wqb, n8);
    cast_kernel<<<(n8 + 255) / 256, 256, 0, stream>>>(Wo, Wob, n8);
    n8 = NKV * DK * DM / 8;
    cast_kernel<<<(n8 + 255) / 256, 256, 0, stream>>>(Wk, Wkb, n8);
    cast_kernel<<<(n8 + 255) / 256, 256, 0, stream>>>(Wv, Wvb, n8);
  }
  // projections
  {
    int M = NB * SQ;
    gemm_bt<<<(M / 128) * (DM / 128), 256, 0, stream>>>(xb, Wqb, bq, qf32, M, DM, DM);
    gemm_bt<<<(M / 128) * ((NKV * DK) / 128), 256, 0, stream>>>(xb, Wkb, bk, kf32, M, NKV * DK, DM);
    gemm_bt<<<(M / 128) * ((NKV * DK) / 128), 256, 0, stream>>>(xb, Wvb, bv, vf32, M, NKV * DK, DM);
  }
  // norm + rope (q,k), transpose v
  {
    int waves = NB * SQ * (NH + NKV);
    normrope_qk<<<waves / 4, 256, 0, stream>>>(qf32, kf32, qw, kw, qbh, kbh);
    vtrans<<<NB * NKV * (SQ / 64), 256, 0, stream>>>(vf32, vth);
  }
  // attention
  {
    dim3 g(SQ / 64, NH, NB);
    attn<<<g, 256, 0, stream>>>(qbh, kbh, vth, aout);
  }
  // output projection
  {
    int M = NB * SQ;
    gemm_bt<<<(M / 128) * (DM / 128), 256, 0, stream>>>(aout, Wob, bo, outp, M, DM, DM);
  }
}

// Round 4
// 300.551 us; speedup vs baseline: 2.3313x; 1.2347x over previous
//
#include <hip/hip_runtime.h>
#include <hip/hip_bf16.h>
#include <stdint.h>

#define DM 2048
#define SQ 2048
#define NB 2
#define NH 16
#define NKV 4
#define DK 128

typedef unsigned short u16;
typedef unsigned int u32;
typedef __attribute__((ext_vector_type(8))) __bf16 bf16x8;
typedef __attribute__((ext_vector_type(4))) float f32x4;
typedef __attribute__((ext_vector_type(8))) u16 u16x8;

__device__ __forceinline__ u16 f2bf(float f) {
  u32 x = __builtin_bit_cast(u32, f);
  x += 0x7fffu + ((x >> 16) & 1u);
  return (u16)(x >> 16);
}

__device__ __forceinline__ f32x4 mfma16(bf16x8 a, bf16x8 b, f32x4 c) {
  return __builtin_amdgcn_mfma_f32_16x16x32_bf16(a, b, c, 0, 0, 0);
}

#define GLDS16(g, l)                                                          \
  __builtin_amdgcn_global_load_lds(                                           \
      (const __attribute__((address_space(1))) void*)(g),                     \
      (__attribute__((address_space(3))) void*)(l), 16, 0, 0)

// ---------------- cast fp32 -> bf16 (8 elems/thread) ----------------
__global__ void cast_kernel(const float* __restrict__ src, u16* __restrict__ dst, int n8) {
  int i = blockIdx.x * blockDim.x + threadIdx.x;
  if (i >= n8) return;
  const float4* s4 = (const float4*)src;
  float4 a = s4[2 * i], b = s4[2 * i + 1];
  u16x8 v;
  v[0] = f2bf(a.x); v[1] = f2bf(a.y); v[2] = f2bf(a.z); v[3] = f2bf(a.w);
  v[4] = f2bf(b.x); v[5] = f2bf(b.y); v[6] = f2bf(b.z); v[7] = f2bf(b.w);
  *(u16x8*)(dst + 8 * (size_t)i) = v;
}

// ---------------- GEMM: C[M][N] = A[M][K](bf16) * W[N][K]^T(bf16) + bias ----------------
__global__ __launch_bounds__(256) void gemm_bt(
    const u16* __restrict__ A, const u16* __restrict__ W,
    const float* __restrict__ bias, float* __restrict__ C,
    int M, int N, int K) {
  __shared__ u16 As[128 * 64];
  __shared__ u16 Bs[128 * 64];
  const int tid = threadIdx.x;
  const int w = tid >> 6, l = tid & 63;
  const int hi = l >> 4, lo = l & 15;
  const int MB = M >> 7;
  const int bm = blockIdx.x % MB, bn = blockIdx.x / MB;
  const int wr = w >> 1, wc = w & 1;
  const int lr8 = l >> 3, lc = l & 7;
  f32x4 acc[4][4] = {};
  for (int kt = 0; kt < K; kt += 64) {
#pragma unroll
    for (int i = 0; i < 4; ++i) {
      int row = w * 32 + i * 8 + lr8;
      int gc = lc ^ (row & 7);
      GLDS16(A + (size_t)(bm * 128 + row) * K + kt + gc * 8, &As[(w * 32 + i * 8) * 64]);
    }
#pragma unroll
    for (int i = 0; i < 4; ++i) {
      int row = w * 32 + i * 8 + lr8;
      int gc = lc ^ (row & 7);
      GLDS16(W + (size_t)(bn * 128 + row) * K + kt + gc * 8, &Bs[(w * 32 + i * 8) * 64]);
    }
    __syncthreads();
#pragma unroll
    for (int kk = 0; kk < 2; ++kk) {
      bf16x8 af[4], bf[4];
#pragma unroll
      for (int mi = 0; mi < 4; ++mi) {
        int row = wr * 64 + mi * 16 + lo;
        af[mi] = *(const bf16x8*)&As[row * 64 + (((kk * 4 + hi) ^ (row & 7)) * 8)];
      }
#pragma unroll
      for (int ni = 0; ni < 4; ++ni) {
        int row = wc * 64 + ni * 16 + lo;
        bf[ni] = *(const bf16x8*)&Bs[row * 64 + (((kk * 4 + hi) ^ (row & 7)) * 8)];
      }
#pragma unroll
      for (int mi = 0; mi < 4; ++mi)
#pragma unroll
        for (int ni = 0; ni < 4; ++ni)
          acc[mi][ni] = mfma16(af[mi], bf[ni], acc[mi][ni]);
    }
    __syncthreads();
  }
#pragma unroll
  for (int mi = 0; mi < 4; ++mi) {
#pragma unroll
    for (int ni = 0; ni < 4; ++ni) {
      int col = bn * 128 + wc * 64 + ni * 16 + lo;
      float bv = bias[col];
#pragma unroll
      for (int r = 0; r < 4; ++r) {
        int rowg = bm * 128 + wr * 64 + mi * 16 + hi * 4 + r;
        C[(size_t)rowg * N + col] = acc[mi][ni][r] + bv;
      }
    }
  }
}

// ---------------- RMSNorm + RoPE for q,k; one wave per head-vector ----------------
// q additionally pre-scaled by 1/sqrt(DK) so attn needs no scale.
__global__ void normrope_qk(const float* __restrict__ qf, const float* __restrict__ kf,
                            const float* __restrict__ qw, const float* __restrict__ kw,
                            u16* __restrict__ qb, u16* __restrict__ kb) {
  int gw = (int)((blockIdx.x * (size_t)blockDim.x + threadIdx.x) >> 6);
  int lane = threadIdx.x & 63;
  int bs = gw / (NH + NKV), j = gw % (NH + NKV);
  int b = bs / SQ, s = bs % SQ;
  const float* src;
  const float* wgt;
  u16* dst;
  float post = 1.0f;
  if (j < NH) {
    src = qf + (size_t)bs * DM + j * DK;
    wgt = qw;
    dst = qb + ((size_t)(b * NH + j) * SQ + s) * DK;
    post = 0.08838834764831845f;  // 1/sqrt(128)
  } else {
    int kh = j - NH;
    src = kf + (size_t)bs * (NKV * DK) + kh * DK;
    wgt = kw;
    dst = kb + ((size_t)(b * NKV + kh) * SQ + s) * DK;
  }
  float2 xv = *(const float2*)(src + 2 * lane);
  float ss = xv.x * xv.x + xv.y * xv.y;
#pragma unroll
  for (int m = 1; m < 64; m <<= 1) ss += __shfl_xor(ss, m);
  float inv = rsqrtf(ss * (1.0f / DK) + 1e-8f);
  float x1 = xv.x * inv * wgt[2 * lane];
  float x2 = xv.y * inv * wgt[2 * lane + 1];
  float theta = (float)s * expf((float)lane * (-9.2103403720f / 64.0f));
  float sn, cs;
  sincosf(theta, &sn, &cs);
  float o1 = (x1 * cs - x2 * sn) * post;
  float o2 = (x1 * sn + x2 * cs) * post;
  u32 pack = (u32)f2bf(o1) | ((u32)f2bf(o2) << 16);
  *(u32*)(dst + 2 * lane) = pack;
}

// ---------------- V: cast + transpose to [B][NKV][DK][SQ] ----------------
__global__ __launch_bounds__(256) void vtrans(const float* __restrict__ vf, u16* __restrict__ vt) {
  __shared__ u16 T[128 * 72];
  int bid = blockIdx.x;
  int st = bid % (SQ / 64);
  int rem = bid / (SQ / 64);
  int vh = rem % NKV, b = rem / NKV;
  int s0 = st * 64;
  int t = threadIdx.x;
#pragma unroll
  for (int it = 0; it < 8; ++it) {
    int idx = it * 256 + t;  // 0..2047
    int sl = idx >> 5;       // 0..63
    int c4 = idx & 31;       // float4 within 128
    float4 v = *(const float4*)(vf + (size_t)(b * SQ + s0 + sl) * (NKV * DK) + vh * DK + c4 * 4);
    T[(c4 * 4 + 0) * 72 + sl] = f2bf(v.x);
    T[(c4 * 4 + 1) * 72 + sl] = f2bf(v.y);
    T[(c4 * 4 + 2) * 72 + sl] = f2bf(v.z);
    T[(c4 * 4 + 3) * 72 + sl] = f2bf(v.w);
  }
  __syncthreads();
#pragma unroll
  for (int it = 0; it < 4; ++it) {
    int idx = it * 256 + t;  // 0..1023
    int d = idx >> 3;        // 0..127
    int ch = idx & 7;        // 0..7
    u16x8 v = *(const u16x8*)&T[d * 72 + ch * 8];
    *(u16x8*)(vt + ((size_t)(b * NKV + vh) * DK + d) * SQ + s0 + ch * 8) = v;
  }
}

// ---------------- flash attention (paired q-tiles, dbuf K/V) ----------------
// grid (SQ/128 pairs, NH, NB), 256 thr = 4 waves. Block handles q-tiles
// {pr, 31-pr} -> exactly 33 k-tile iters per block (uniform). K/V tiles
// double-buffered via global_load_lds (prefetch overlaps compute).
__global__ __launch_bounds__(256) void attn(const u16* __restrict__ qb, const u16* __restrict__ kb,
                                            const u16* __restrict__ vt, u16* __restrict__ out) {
  __shared__ u16 Ks[2][64 * 128];
  __shared__ u16 Vs[2][128 * 64];
  __shared__ u16 P[4][16 * 64];
  const int w = threadIdx.x >> 6, l = threadIdx.x & 63;
  const int hi = l >> 4, lo = l & 15;
  const int pr = blockIdx.x, h = blockIdx.y, b = blockIdx.z;
  const int kvh = h >> 2;
  const u16* Q = qb + (size_t)(b * NH + h) * SQ * DK;
  const u16* K = kb + (size_t)(b * NKV + kvh) * SQ * DK;
  const u16* V = vt + (size_t)(b * NKV + kvh) * DK * SQ;

  auto stageKV = [&](int buf, int kt) {
#pragma unroll
    for (int i = 0; i < 4; ++i) {
      int rb = w * 16 + i * 4;
      int row = rb + (l >> 4);
      int gc = (l & 15) ^ (row & 7);
      GLDS16(K + (size_t)(kt + row) * DK + gc * 8, &Ks[buf][rb * 128]);
    }
#pragma unroll
    for (int i = 0; i < 4; ++i) {
      int rb = w * 32 + i * 8;
      int row = rb + (l >> 3);
      int gc = (l & 7) ^ (row & 7);
      GLDS16(V + (size_t)row * SQ + kt + gc * 8, &Vs[buf][rb * 64]);
    }
  };

#pragma unroll 1
  for (int seg = 0; seg < 2; ++seg) {
    const int qt = seg ? (SQ / 64 - 1 - pr) : pr;
    const int q0 = qt * 64 + w * 16;
    bf16x8 qf[4];
#pragma unroll
    for (int kk = 0; kk < 4; ++kk)
      qf[kk] = *(const bf16x8*)(Q + (size_t)(q0 + lo) * DK + kk * 32 + hi * 8);
    f32x4 oacc[8] = {};
    float mrun[4] = {-3e38f, -3e38f, -3e38f, -3e38f};
    float lrun[4] = {0.f, 0.f, 0.f, 0.f};
    const int nt = qt + 1;
    stageKV(0, 0);
    __syncthreads();
#pragma unroll 1
    for (int ti = 0; ti < nt; ++ti) {
      const int cur = ti & 1;
      if (ti + 1 < nt) stageKV(cur ^ 1, (ti + 1) * 64);
      const int kt = ti * 64;
      // ---- QK^T
      f32x4 sfr[4];
      __builtin_amdgcn_s_setprio(1);
#pragma unroll
      for (int cb = 0; cb < 4; ++cb) {
        f32x4 sf = {};
#pragma unroll
        for (int kk = 0; kk < 4; ++kk) {
          int row = cb * 16 + lo;
          bf16x8 kfr = *(const bf16x8*)&Ks[cur][row * 128 + (((kk * 4 + hi) ^ (row & 7)) * 8)];
          sf = mfma16(qf[kk], kfr, sf);
        }
        sfr[cb] = sf;
      }
      __builtin_amdgcn_s_setprio(0);
      // ---- causal mask: only the diagonal tile can violate causality
      if (ti == nt - 1) {
#pragma unroll
        for (int cb = 0; cb < 4; ++cb)
#pragma unroll
          for (int r = 0; r < 4; ++r) {
            int rowq = q0 + hi * 4 + r;
            int col = kt + cb * 16 + lo;
            if (col > rowq) sfr[cb][r] = -1e30f;
          }
      }
      // ---- online softmax over 64 cols (Q pre-scaled)
      float fsc[4];
#pragma unroll
      for (int r = 0; r < 4; ++r) {
        float t = fmaxf(fmaxf(sfr[0][r], sfr[1][r]), fmaxf(sfr[2][r], sfr[3][r]));
        t = fmaxf(t, __shfl_xor(t, 1));
        t = fmaxf(t, __shfl_xor(t, 2));
        t = fmaxf(t, __shfl_xor(t, 4));
        t = fmaxf(t, __shfl_xor(t, 8));
        float mnew = fmaxf(mrun[r], t);
        fsc[r] = __expf(mrun[r] - mnew);
        mrun[r] = mnew;
        int prow = hi * 4 + r;
        float rs = 0.f;
#pragma unroll
        for (int cb = 0; cb < 4; ++cb) {
          float p = __expf(sfr[cb][r] - mnew);
          rs += p;
          int chunk = cb * 2 + (lo >> 3);
          P[w][prow * 64 + ((chunk ^ (prow & 7)) * 8) + (lo & 7)] = f2bf(p);
        }
        rs += __shfl_xor(rs, 1);
        rs += __shfl_xor(rs, 2);
        rs += __shfl_xor(rs, 4);
        rs += __shfl_xor(rs, 8);
        lrun[r] = lrun[r] * fsc[r] + rs;
      }
      // ---- rescale O
#pragma unroll
      for (int fr = 0; fr < 8; ++fr)
#pragma unroll
        for (int r = 0; r < 4; ++r) oacc[fr][r] *= fsc[r];
      // ---- PV
      __builtin_amdgcn_s_setprio(1);
#pragma unroll
      for (int half = 0; half < 2; ++half) {
        bf16x8 pa = *(const bf16x8*)&P[w][lo * 64 + (((half * 4 + hi) ^ (lo & 7)) * 8)];
#pragma unroll
        for (int fr = 0; fr < 8; ++fr) {
          int row = fr * 16 + lo;
          bf16x8 vfr = *(const bf16x8*)&Vs[cur][row * 64 + (((half * 4 + hi) ^ (row & 7)) * 8)];
          oacc[fr] = mfma16(pa, vfr, oacc[fr]);
        }
      }
      __builtin_amdgcn_s_setprio(0);
      __syncthreads();
    }
    float invl[4];
#pragma unroll
    for (int r = 0; r < 4; ++r) invl[r] = 1.0f / lrun[r];
#pragma unroll
    for (int fr = 0; fr < 8; ++fr) {
#pragma unroll
      for (int r = 0; r < 4; ++r) {
        int row = b * SQ + q0 + hi * 4 + r;
        int col = h * DK + fr * 16 + lo;
        out[(size_t)row * DM + col] = f2bf(oacc[fr][r] * invl[r]);
      }
    }
  }
}

extern "C" void kernel_launch(void* const* d_in, const int* in_sizes, int n_in,
                              void* d_out, int out_size, void* d_ws, size_t ws_size,
                              hipStream_t stream) {
  const float* x = (const float*)d_in[0];
  const float* Wq = (const float*)d_in[1];
  const float* bq = (const float*)d_in[2];
  const float* Wk = (const float*)d_in[3];
  const float* bk = (const float*)d_in[4];
  const float* Wv = (const float*)d_in[5];
  const float* bv = (const float*)d_in[6];
  const float* Wo = (const float*)d_in[7];
  const float* bo = (const float*)d_in[8];
  const float* qw = (const float*)d_in[9];
  const float* kw = (const float*)d_in[10];
  float* outp = (float*)d_out;

  char* ws = (char*)d_ws;
  size_t off = 0;
  auto alloc = [&](size_t bytes) {
    char* p = ws + off;
    off += (bytes + 255) & ~(size_t)255;
    return p;
  };
  u16* xb = (u16*)alloc((size_t)NB * SQ * DM * 2);
  u16* Wqb = (u16*)alloc((size_t)DM * DM * 2);
  u16* Wkb = (u16*)alloc((size_t)NKV * DK * DM * 2);
  u16* Wvb = (u16*)alloc((size_t)NKV * DK * DM * 2);
  u16* Wob = (u16*)alloc((size_t)DM * DM * 2);
  float* qf32 = (float*)alloc((size_t)NB * SQ * DM * 4);
  float* kf32 = (float*)alloc((size_t)NB * SQ * NKV * DK * 4);
  float* vf32 = (float*)alloc((size_t)NB * SQ * NKV * DK * 4);
  u16* qbh = (u16*)alloc((size_t)NB * NH * SQ * DK * 2);
  u16* kbh = (u16*)alloc((size_t)NB * NKV * SQ * DK * 2);
  u16* vth = (u16*)alloc((size_t)NB * NKV * DK * SQ * 2);
  u16* aout = (u16*)alloc((size_t)NB * SQ * DM * 2);

  // casts
  {
    int n8 = NB * SQ * DM / 8;
    cast_kernel<<<(n8 + 255) / 256, 256, 0, stream>>>(x, xb, n8);
    n8 = DM * DM / 8;
    cast_kernel<<<(n8 + 255) / 256, 256, 0, stream>>>(Wq, Wqb, n8);
    cast_kernel<<<(n8 + 255) / 256, 256, 0, stream>>>(Wo, Wob, n8);
    n8 = NKV * DK * DM / 8;
    cast_kernel<<<(n8 + 255) / 256, 256, 0, stream>>>(Wk, Wkb, n8);
    cast_kernel<<<(n8 + 255) / 256, 256, 0, stream>>>(Wv, Wvb, n8);
  }
  // projections
  {
    int M = NB * SQ;
    gemm_bt<<<(M / 128) * (DM / 128), 256, 0, stream>>>(xb, Wqb, bq, qf32, M, DM, DM);
    gemm_bt<<<(M / 128) * ((NKV * DK) / 128), 256, 0, stream>>>(xb, Wkb, bk, kf32, M, NKV * DK, DM);
    gemm_bt<<<(M / 128) * ((NKV * DK) / 128), 256, 0, stream>>>(xb, Wvb, bv, vf32, M, NKV * DK, DM);
  }
  // norm + rope (q,k), transpose v
  {
    int waves = NB * SQ * (NH + NKV);
    normrope_qk<<<waves / 4, 256, 0, stream>>>(qf32, kf32, qw, kw, qbh, kbh);
    vtrans<<<NB * NKV * (SQ / 64), 256, 0, stream>>>(vf32, vth);
  }
  // attention
  {
    dim3 g(SQ / 128, NH, NB);
    attn<<<g, 256, 0, stream>>>(qbh, kbh, vth, aout);
  }
  // output projection
  {
    int M = NB * SQ;
    gemm_bt<<<(M / 128) * (DM / 128), 256, 0, stream>>>(aout, Wob, bo, outp, M, DM, DM);
  }
}